// Round 9
// baseline (154.321 us; speedup 1.0000x reference)
//
#include <hip/hip_runtime.h>
#include <hip/hip_bf16.h>
#include <math.h>

#define NN 4096
#define IN_DIM 256
#define OUT_DIM 128
#define HEADS 4
#define SUB 32
#define MAXDEG 128
#define ETA 0.5f
#define INV_SQRT_SUB 0.17677669529663687f

typedef __attribute__((ext_vector_type(8))) short bf16x8;
typedef __attribute__((ext_vector_type(4))) short s16x4;
typedef __attribute__((ext_vector_type(4))) float f32x4;

static __device__ inline short f2bf(float f) {
    unsigned u = __float_as_uint(f);
    unsigned r = u + 0x7FFFu + ((u >> 16) & 1u);
    return (short)(r >> 16);
}
static __device__ inline float bf2f(short s) {
    return __uint_as_float(((unsigned)(unsigned short)s) << 16);
}
#define MFMA16(a, b, c) __builtin_amdgcn_mfma_f32_16x16x32_bf16(a, b, c, 0, 0, 0)

// ---- K0: Wh/Wl prep | W2 | orth loss partials | adjacency scan (2048 blocks) ----
__global__ __launch_bounds__(256) void fused_small(const float* __restrict__ U,
                                                   const float* __restrict__ PW,
                                                   const float* __restrict__ adj,
                                                   short* __restrict__ Wh,
                                                   short* __restrict__ Wl,
                                                   float* __restrict__ W2,
                                                   float* __restrict__ loss_parts,
                                                   int* __restrict__ nbr,
                                                   int* __restrict__ deg) {
    int b = blockIdx.x;
    int t = threadIdx.x;
    __shared__ float sh[260];
    __shared__ int cnt2[2];

    if (b < 256) {
        float v;
        if (b < 128) {
            int h = b >> 5, s = b & 31;
            v = U[h * IN_DIM * SUB + t * SUB + s];
        } else {
            v = PW[(b - 128) * IN_DIM + t];
        }
        short hi = f2bf(v);
        Wh[b * IN_DIM + t] = hi;
        Wl[b * IN_DIM + t] = f2bf(v - bf2f(hi));
    } else if (b < 384) {
        int hs = b - 256;
        int h = hs >> 5, s = hs & 31;
        sh[t] = U[h * IN_DIM * SUB + t * SUB + s];
        __syncthreads();
        if (t < 128) {
            const float4* pw4 = (const float4*)(PW + t * IN_DIM);
            const float4* u4  = (const float4*)sh;
            float acc = 0.f;
            #pragma unroll 4
            for (int d4 = 0; d4 < 64; ++d4) {
                float4 a = u4[d4], p = pw4[d4];
                acc += a.x * p.x + a.y * p.y + a.z * p.z + a.w * p.w;
            }
            W2[hs * OUT_DIM + t] = acc;       // [hs][o]
        }
    } else if (b < 394) {
        const int pk[10] = {0,0,0,0,1,1,1,2,2,3};
        const int pl[10] = {0,1,2,3,1,2,3,2,3,3};
        int p = b - 384;
        int k = pk[p], l = pl[p];
        int t2 = t & 31;
        int sg = t >> 5;
        const float* Uk = U + k * IN_DIM * SUB;
        const float* Ul = U + l * IN_DIM * SUB;
        float a0 = 0.f, a1 = 0.f, a2 = 0.f, a3 = 0.f;
        #pragma unroll 4
        for (int d = 0; d < IN_DIM; ++d) {
            float ul = Ul[d * SUB + t2];
            float u0 = Uk[d * SUB + sg * 4 + 0];
            float u1 = Uk[d * SUB + sg * 4 + 1];
            float u2 = Uk[d * SUB + sg * 4 + 2];
            float u3 = Uk[d * SUB + sg * 4 + 3];
            a0 += u0 * ul; a1 += u1 * ul; a2 += u2 * ul; a3 += u3 * ul;
        }
        if (k == l) {
            if (sg * 4 + 0 == t2) a0 -= 1.f;
            if (sg * 4 + 1 == t2) a1 -= 1.f;
            if (sg * 4 + 2 == t2) a2 -= 1.f;
            if (sg * 4 + 3 == t2) a3 -= 1.f;
        }
        float local = a0 * a0 + a1 * a1 + a2 * a2 + a3 * a3;
        local += __shfl_xor(local, 32, 64);
        local += __shfl_xor(local, 16, 64);
        local += __shfl_xor(local, 8, 64);
        local += __shfl_xor(local, 4, 64);
        local += __shfl_xor(local, 2, 64);
        local += __shfl_xor(local, 1, 64);
        if ((t & 63) == 0) sh[256 + (t >> 6)] = local;
        __syncthreads();
        if (t == 0) loss_parts[p] = sh[256] + sh[257] + sh[258] + sh[259];
    } else {
        // adjacency scan: 2 rows per block, register-prefetched
        int sb = b - 394;
        int half = t >> 7, u = t & 127;
        int row = sb * 2 + half;
        const float4* row4 = (const float4*)(adj + (size_t)row * NN);
        float4 v[8];
        #pragma unroll
        for (int k = 0; k < 8; ++k) v[k] = row4[u + k * 128];
        if (u == 0) cnt2[half] = 0;
        __syncthreads();
        int* nrow = nbr + row * MAXDEG;
        #pragma unroll
        for (int k = 0; k < 8; ++k) {
            int j0 = (u + k * 128) * 4;
            if (v[k].x > 0.5f) { int p = atomicAdd(&cnt2[half], 1); if (p < MAXDEG) nrow[p] = j0; }
            if (v[k].y > 0.5f) { int p = atomicAdd(&cnt2[half], 1); if (p < MAXDEG) nrow[p] = j0 + 1; }
            if (v[k].z > 0.5f) { int p = atomicAdd(&cnt2[half], 1); if (p < MAXDEG) nrow[p] = j0 + 2; }
            if (v[k].w > 0.5f) { int p = atomicAdd(&cnt2[half], 1); if (p < MAXDEG) nrow[p] = j0 + 3; }
        }
        __syncthreads();
        int dgr = cnt2[half] < MAXDEG ? cnt2[half] : MAXDEG;
        if (u >= dgr) nrow[u] = 0;         // zero-fill tail so padded reads hit row 0
        if (u == 0) deg[row] = dgr;
    }
}

// ---- K1: [ZT | P] = H @ W^T via split-bf16 MFMA (3-term, fp32-accurate) ----
#define LDA 264
__global__ __launch_bounds__(256) void ztp_mfma(const float* __restrict__ H,
                                                const short* __restrict__ Wh,
                                                const short* __restrict__ Wl,
                                                float* __restrict__ ZT,
                                                float* __restrict__ P) {
    __shared__ short Ah[16 * LDA];
    __shared__ short Al[16 * LDA];
    int t = threadIdx.x, b = blockIdx.x;
    int m0 = (b >> 1) * 16, chalf = b & 1;

    {
        int r = t >> 4, dbase = (t & 15) * 16;
        const float4* src = (const float4*)(H + (size_t)(m0 + r) * IN_DIM + dbase);
        #pragma unroll
        for (int q = 0; q < 4; ++q) {
            float4 f = src[q];
            float fv[4] = {f.x, f.y, f.z, f.w};
            s16x4 hi, lo;
            #pragma unroll
            for (int j = 0; j < 4; ++j) {
                short h = f2bf(fv[j]);
                hi[j] = h;
                lo[j] = f2bf(fv[j] - bf2f(h));
            }
            *(s16x4*)&Ah[r * LDA + dbase + q * 4] = hi;
            *(s16x4*)&Al[r * LDA + dbase + q * 4] = lo;
        }
    }
    __syncthreads();

    int wave = t >> 6, lane = t & 63;
    int c0 = chalf * 128 + wave * 32;
    int arow = lane & 15, agrp = lane >> 4;

    const short* ahp = &Ah[arow * LDA + agrp * 8];
    const short* alp = &Al[arow * LDA + agrp * 8];
    const short* bh0 = Wh + (size_t)(c0 + arow) * IN_DIM + agrp * 8;
    const short* bl0 = Wl + (size_t)(c0 + arow) * IN_DIM + agrp * 8;
    const short* bh1 = bh0 + 16 * IN_DIM;
    const short* bl1 = bl0 + 16 * IN_DIM;

    f32x4 acc0 = {0.f, 0.f, 0.f, 0.f};
    f32x4 acc1 = {0.f, 0.f, 0.f, 0.f};

    #pragma unroll
    for (int kk = 0; kk < 8; ++kk) {
        int d0 = kk * 32;
        bf16x8 a_h = *(const bf16x8*)(ahp + d0);
        bf16x8 a_l = *(const bf16x8*)(alp + d0);
        bf16x8 b0h = *(const bf16x8*)(bh0 + d0);
        bf16x8 b0l = *(const bf16x8*)(bl0 + d0);
        bf16x8 b1h = *(const bf16x8*)(bh1 + d0);
        bf16x8 b1l = *(const bf16x8*)(bl1 + d0);
        acc0 = MFMA16(a_h, b0h, acc0);
        acc0 = MFMA16(a_h, b0l, acc0);
        acc0 = MFMA16(a_l, b0h, acc0);
        acc1 = MFMA16(a_h, b1h, acc1);
        acc1 = MFMA16(a_h, b1l, acc1);
        acc1 = MFMA16(a_l, b1h, acc1);
    }

    float* dst = chalf ? P : ZT;
    int colbase = c0 - chalf * 128;
    #pragma unroll
    for (int i = 0; i < 4; ++i) {
        int row = m0 + agrp * 4 + i;
        dst[(size_t)row * 128 + colbase + arow]      = acc0[i];
        dst[(size_t)row * 128 + colbase + 16 + arow] = acc1[i];
    }
}

// ---- K2: attention from precomputed nbr lists + fused epilogue ----
__global__ __launch_bounds__(128) void attn_core(const float* __restrict__ ZT,
                                                 const float* __restrict__ Pm,
                                                 const float* __restrict__ W2,
                                                 const int* __restrict__ nbr,
                                                 const int* __restrict__ deg,
                                                 const float* __restrict__ threshold,
                                                 const float* __restrict__ loss_parts,
                                                 float* __restrict__ out) {
    int i = blockIdx.x;
    int t = threadIdx.x;
    __shared__ int   nbr_s[MAXDEG];
    __shared__ float e_s[MAXDEG][HEADS];
    __shared__ float z_s[128];
    __shared__ float agg_s[128];

    if (i == 0 && t == 0) {
        float L = 0.f;
        #pragma unroll
        for (int p = 0; p < 10; ++p) L += loss_parts[p];
        out[(size_t)NN * OUT_DIM] = L;
    }

    // issue all front loads immediately (latency hides under barriers/phases)
    int dg = deg[i];
    int nb = nbr[i * MAXDEG + t];
    float zq = ZT[(size_t)i * 128 + t];
    float pval = Pm[(size_t)i * 128 + t];
    float th = threshold[t];

    nbr_s[t] = nb;
    z_s[t] = zq;
    __syncthreads();

    // phase B: lane=(neighbor jj0=t>>2, head h=t&3); full 32-dot, no shuffles
    int jj0 = t >> 2, h = t & 3;
    int ntiles = (dg + 31) >> 5;
    const float4* qr = (const float4*)(&z_s[h * 32]);
    for (int tile = 0; tile < ntiles; ++tile) {
        int jj = tile * 32 + jj0;
        int j = nbr_s[jj];                       // tail entries are 0 (safe)
        const float4* zr = (const float4*)(ZT + (size_t)j * 128 + h * 32);
        float acc = 0.f;
        #pragma unroll
        for (int k = 0; k < 8; ++k) {
            float4 z = zr[k];
            float4 q = qr[k];
            acc += z.x * q.x + z.y * q.y + z.z * q.z + z.w * q.w;
        }
        e_s[jj][h] = (jj < dg) ? __expf(acc * INV_SQRT_SUB) : 0.f;
    }
    __syncthreads();

    // phase C: weighted aggregation, 8 scattered loads in flight
    int hh = t >> 5;
    float accV = 0.f, accS = 0.f;
    const float* zbase = ZT + t;
    for (int jj = 0; jj < dg; jj += 8) {
        int j0 = nbr_s[jj],     j1 = nbr_s[jj + 1];
        int j2 = nbr_s[jj + 2], j3 = nbr_s[jj + 3];
        int j4 = nbr_s[jj + 4], j5 = nbr_s[jj + 5];
        int j6 = nbr_s[jj + 6], j7 = nbr_s[jj + 7];
        float v0 = zbase[(size_t)j0 * 128], v1 = zbase[(size_t)j1 * 128];
        float v2 = zbase[(size_t)j2 * 128], v3 = zbase[(size_t)j3 * 128];
        float v4 = zbase[(size_t)j4 * 128], v5 = zbase[(size_t)j5 * 128];
        float v6 = zbase[(size_t)j6 * 128], v7 = zbase[(size_t)j7 * 128];
        float e0 = e_s[jj][hh],     e1 = e_s[jj + 1][hh];
        float e2 = e_s[jj + 2][hh], e3 = e_s[jj + 3][hh];
        float e4 = e_s[jj + 4][hh], e5 = e_s[jj + 5][hh];
        float e6 = e_s[jj + 6][hh], e7 = e_s[jj + 7][hh];
        accV += e0 * v0 + e1 * v1 + e2 * v2 + e3 * v3
              + e4 * v4 + e5 * v5 + e6 * v6 + e7 * v7;
        accS += (e0 + e1) + (e2 + e3) + (e4 + e5) + (e6 + e7);
    }
    agg_s[t] = accV * (ETA / accS);
    __syncthreads();

    // fused epilogue: out[i][t] = soft_thresh(P[i][t] + sum_hs agg[hs]*W2[hs][t])
    float val = pval;
    #pragma unroll 4
    for (int q4 = 0; q4 < 32; ++q4) {
        int hs = q4 * 4;
        float w0 = W2[(hs + 0) * 128 + t];     // coalesced, L2-resident
        float w1 = W2[(hs + 1) * 128 + t];
        float w2v = W2[(hs + 2) * 128 + t];
        float w3 = W2[(hs + 3) * 128 + t];
        float4 a = *(const float4*)&agg_s[hs]; // LDS broadcast
        val += a.x * w0 + a.y * w1 + a.z * w2v + a.w * w3;
    }
    float av = fabsf(val) - th;
    out[(size_t)i * 128 + t] = (av > 0.f) ? copysignf(av, val) : 0.f;
}

extern "C" void kernel_launch(void* const* d_in, const int* in_sizes, int n_in,
                              void* d_out, int out_size, void* d_ws, size_t ws_size,
                              hipStream_t stream) {
    const float* H   = (const float*)d_in[0];
    const float* adj = (const float*)d_in[1];
    const float* U   = (const float*)d_in[2];
    const float* thr = (const float*)d_in[3];
    const float* PW  = (const float*)d_in[4];
    float* out = (float*)d_out;

    char* ws = (char*)d_ws;
    float* ZT    = (float*)(ws);                       // 2 MB
    float* P     = (float*)(ws + (size_t)2097152);     // 2 MB
    float* W2    = (float*)(ws + (size_t)4194304);     // 64 KB
    short* Wh    = (short*)(ws + (size_t)4259840);     // 128 KB
    short* Wl    = (short*)(ws + (size_t)4390912);     // 128 KB
    float* lossp = (float*)(ws + (size_t)4521984);     // 40 B
    int*   nbr   = (int*)  (ws + (size_t)4530176);     // 2 MB
    int*   deg   = (int*)  (ws + (size_t)6627328);     // 16 KB

    fused_small<<<394 + NN / 2, 256, 0, stream>>>(U, PW, adj, Wh, Wl, W2, lossp, nbr, deg);
    ztp_mfma<<<NN / 16 * 2, 256, 0, stream>>>(H, Wh, Wl, ZT, P);
    attn_core<<<NN, 128, 0, stream>>>(ZT, P, W2, nbr, deg, thr, lossp, out);
}

// Round 10
// 148.194 us; speedup vs baseline: 1.0413x; 1.0413x over previous
//
#include <hip/hip_runtime.h>
#include <hip/hip_bf16.h>
#include <math.h>

#define NN 4096
#define IN_DIM 256
#define OUT_DIM 128
#define HEADS 4
#define SUB 32
#define MAXDEG 128
#define ETA 0.5f
#define INV_SQRT_SUB 0.17677669529663687f

typedef __attribute__((ext_vector_type(8))) short bf16x8;
typedef __attribute__((ext_vector_type(4))) float f32x4;

static __device__ inline short f2bf(float f) {
    unsigned u = __float_as_uint(f);
    unsigned r = u + 0x7FFFu + ((u >> 16) & 1u);
    return (short)(r >> 16);
}
static __device__ inline float bf2f(short s) {
    return __uint_as_float(((unsigned)(unsigned short)s) << 16);
}
#define MFMA16(a, b, c) __builtin_amdgcn_mfma_f32_16x16x32_bf16(a, b, c, 0, 0, 0)

// ---- K1: [ztp 512 | W2 128 | loss 10 | scan 2048] all-independent front ----
#define BLD 264   // B LDS row stride in shorts (pad -> 2-way-only conflicts)
__global__ __launch_bounds__(256) void front(const float* __restrict__ H,
                                             const float* __restrict__ U,
                                             const float* __restrict__ PW,
                                             const float* __restrict__ adj,
                                             float* __restrict__ ZT,
                                             float* __restrict__ P,
                                             float* __restrict__ W2,
                                             float* __restrict__ loss_parts,
                                             int* __restrict__ nbr,
                                             int* __restrict__ deg) {
    int b = blockIdx.x, t = threadIdx.x;
    __shared__ short Bh[32 * BLD];
    __shared__ short Bl[32 * BLD];
    __shared__ float sh[260];
    __shared__ int cnt2[2];

    if (b < 512) {
        // ---- ztp: block = 64 rows x 32 cols, self-contained B conversion ----
        int mtile = b >> 3, cblk = b & 7;
        int m0 = mtile * 64;

        // stage B panel: 32 cols x 256 d as split-bf16 into LDS
        if (cblk < 4) {
            // cols = head h=cblk, all s: U[h][d][s], s-contiguous -> coalesced
            int s = t & 31, dgrp = t >> 5;
            const float* ub = U + cblk * IN_DIM * SUB;
            #pragma unroll 4
            for (int k = 0; k < 32; ++k) {
                int d = dgrp * 32 + k;
                float v = ub[d * SUB + s];
                short hi = f2bf(v);
                Bh[s * BLD + d] = hi;
                Bl[s * BLD + d] = f2bf(v - bf2f(hi));
            }
        } else {
            // cols = PW rows o0..o0+32, row-major stream
            int oo = t >> 3, o0 = (cblk - 4) * 32;
            const float* pr = PW + (size_t)(o0 + oo) * IN_DIM + (t & 7) * 32;
            #pragma unroll 4
            for (int k = 0; k < 32; ++k) {
                int d = (t & 7) * 32 + k;
                float v = pr[k];
                short hi = f2bf(v);
                Bh[oo * BLD + d] = hi;
                Bl[oo * BLD + d] = f2bf(v - bf2f(hi));
            }
        }
        __syncthreads();

        int w = t >> 6, lane = t & 63;
        int arow = lane & 15, agrp = lane >> 4;
        const float* hrow = H + (size_t)(m0 + w * 16 + arow) * IN_DIM;
        const short* bh0 = &Bh[arow * BLD];
        const short* bl0 = &Bl[arow * BLD];
        const short* bh1 = &Bh[(16 + arow) * BLD];
        const short* bl1 = &Bl[(16 + arow) * BLD];

        f32x4 acc0 = {0.f, 0.f, 0.f, 0.f};
        f32x4 acc1 = {0.f, 0.f, 0.f, 0.f};

        #pragma unroll
        for (int kk = 0; kk < 8; ++kk) {
            int d0 = agrp * 8 + kk * 32;
            float4 f0 = *(const float4*)(hrow + d0);
            float4 f1 = *(const float4*)(hrow + d0 + 4);
            float fv[8] = {f0.x, f0.y, f0.z, f0.w, f1.x, f1.y, f1.z, f1.w};
            bf16x8 a_h, a_l;
            #pragma unroll
            for (int j = 0; j < 8; ++j) {
                short hi = f2bf(fv[j]);
                a_h[j] = hi;
                a_l[j] = f2bf(fv[j] - bf2f(hi));
            }
            bf16x8 b0h = *(const bf16x8*)(bh0 + d0);
            bf16x8 b0l = *(const bf16x8*)(bl0 + d0);
            bf16x8 b1h = *(const bf16x8*)(bh1 + d0);
            bf16x8 b1l = *(const bf16x8*)(bl1 + d0);
            acc0 = MFMA16(a_h, b0h, acc0);
            acc0 = MFMA16(a_h, b0l, acc0);
            acc0 = MFMA16(a_l, b0h, acc0);
            acc1 = MFMA16(a_h, b1h, acc1);
            acc1 = MFMA16(a_h, b1l, acc1);
            acc1 = MFMA16(a_l, b1h, acc1);
        }

        // C/D: col = lane&15, row = (lane>>4)*4 + reg
        int c0 = cblk * 32;
        float* dst = (c0 < 128) ? ZT : P;
        int colbase = (c0 < 128) ? c0 : c0 - 128;
        #pragma unroll
        for (int i = 0; i < 4; ++i) {
            int row = m0 + w * 16 + agrp * 4 + i;
            dst[(size_t)row * 128 + colbase + arow]      = acc0[i];
            dst[(size_t)row * 128 + colbase + 16 + arow] = acc1[i];
        }
    } else if (b < 640) {
        // ---- W2[hs][o] = <U[:,hs], PW[o,:]> ----
        int hs = b - 512;
        int h = hs >> 5, s = hs & 31;
        sh[t] = U[h * IN_DIM * SUB + t * SUB + s];
        __syncthreads();
        if (t < 128) {
            const float4* pw4 = (const float4*)(PW + t * IN_DIM);
            const float4* u4  = (const float4*)sh;
            float acc = 0.f;
            #pragma unroll 4
            for (int d4 = 0; d4 < 64; ++d4) {
                float4 a = u4[d4], p = pw4[d4];
                acc += a.x * p.x + a.y * p.y + a.z * p.z + a.w * p.w;
            }
            W2[hs * OUT_DIM + t] = acc;       // [hs][o]
        }
    } else if (b < 650) {
        // ---- orth loss partials ----
        const int pk[10] = {0,0,0,0,1,1,1,2,2,3};
        const int pl[10] = {0,1,2,3,1,2,3,2,3,3};
        int p = b - 640;
        int k = pk[p], l = pl[p];
        int t2 = t & 31;
        int sg = t >> 5;
        const float* Uk = U + k * IN_DIM * SUB;
        const float* Ul = U + l * IN_DIM * SUB;
        float a0 = 0.f, a1 = 0.f, a2 = 0.f, a3 = 0.f;
        #pragma unroll 4
        for (int d = 0; d < IN_DIM; ++d) {
            float ul = Ul[d * SUB + t2];
            float u0 = Uk[d * SUB + sg * 4 + 0];
            float u1 = Uk[d * SUB + sg * 4 + 1];
            float u2 = Uk[d * SUB + sg * 4 + 2];
            float u3 = Uk[d * SUB + sg * 4 + 3];
            a0 += u0 * ul; a1 += u1 * ul; a2 += u2 * ul; a3 += u3 * ul;
        }
        if (k == l) {
            if (sg * 4 + 0 == t2) a0 -= 1.f;
            if (sg * 4 + 1 == t2) a1 -= 1.f;
            if (sg * 4 + 2 == t2) a2 -= 1.f;
            if (sg * 4 + 3 == t2) a3 -= 1.f;
        }
        float local = a0 * a0 + a1 * a1 + a2 * a2 + a3 * a3;
        local += __shfl_xor(local, 32, 64);
        local += __shfl_xor(local, 16, 64);
        local += __shfl_xor(local, 8, 64);
        local += __shfl_xor(local, 4, 64);
        local += __shfl_xor(local, 2, 64);
        local += __shfl_xor(local, 1, 64);
        if ((t & 63) == 0) sh[256 + (t >> 6)] = local;
        __syncthreads();
        if (t == 0) loss_parts[p] = sh[256] + sh[257] + sh[258] + sh[259];
    } else {
        // ---- adjacency scan: 2 rows per block, register-prefetched ----
        int sb = b - 650;
        int half = t >> 7, u = t & 127;
        int row = sb * 2 + half;
        const float4* row4 = (const float4*)(adj + (size_t)row * NN);
        float4 v[8];
        #pragma unroll
        for (int k = 0; k < 8; ++k) v[k] = row4[u + k * 128];
        if (u == 0) cnt2[half] = 0;
        __syncthreads();
        int* nrow = nbr + row * MAXDEG;
        #pragma unroll
        for (int k = 0; k < 8; ++k) {
            int j0 = (u + k * 128) * 4;
            if (v[k].x > 0.5f) { int p = atomicAdd(&cnt2[half], 1); if (p < MAXDEG) nrow[p] = j0; }
            if (v[k].y > 0.5f) { int p = atomicAdd(&cnt2[half], 1); if (p < MAXDEG) nrow[p] = j0 + 1; }
            if (v[k].z > 0.5f) { int p = atomicAdd(&cnt2[half], 1); if (p < MAXDEG) nrow[p] = j0 + 2; }
            if (v[k].w > 0.5f) { int p = atomicAdd(&cnt2[half], 1); if (p < MAXDEG) nrow[p] = j0 + 3; }
        }
        __syncthreads();
        int dgr = cnt2[half] < MAXDEG ? cnt2[half] : MAXDEG;
        if (u >= dgr) nrow[u] = 0;         // zero-fill tail -> padded reads hit row 0
        if (u == 0) deg[row] = dgr;
    }
}

// ---- K2: attention from precomputed nbr lists + fused epilogue ----
__global__ __launch_bounds__(128) void attn_core(const float* __restrict__ ZT,
                                                 const float* __restrict__ Pm,
                                                 const float* __restrict__ W2,
                                                 const int* __restrict__ nbr,
                                                 const int* __restrict__ deg,
                                                 const float* __restrict__ threshold,
                                                 const float* __restrict__ loss_parts,
                                                 float* __restrict__ out) {
    int i = blockIdx.x;
    int t = threadIdx.x;
    __shared__ int   nbr_s[MAXDEG];
    __shared__ float e_s[MAXDEG][HEADS];
    __shared__ float z_s[128];
    __shared__ float agg_s[128];

    if (i == 0 && t == 0) {
        float L = 0.f;
        #pragma unroll
        for (int p = 0; p < 10; ++p) L += loss_parts[p];
        out[(size_t)NN * OUT_DIM] = L;
    }

    // issue all front loads immediately (latency hides under barriers/phases)
    int dg = deg[i];
    int nb = nbr[i * MAXDEG + t];
    float zq = ZT[(size_t)i * 128 + t];
    float pval = Pm[(size_t)i * 128 + t];
    float th = threshold[t];

    nbr_s[t] = nb;
    z_s[t] = zq;
    __syncthreads();

    // phase B: lane=(neighbor jj0=t>>2, head h=t&3); full 32-dot, no shuffles
    int jj0 = t >> 2, h = t & 3;
    int ntiles = (dg + 31) >> 5;
    const float4* qr = (const float4*)(&z_s[h * 32]);
    for (int tile = 0; tile < ntiles; ++tile) {
        int jj = tile * 32 + jj0;
        int j = nbr_s[jj];                       // tail entries are 0 (safe)
        const float4* zr = (const float4*)(ZT + (size_t)j * 128 + h * 32);
        float acc = 0.f;
        #pragma unroll
        for (int k = 0; k < 8; ++k) {
            float4 z = zr[k];
            float4 q = qr[k];
            acc += z.x * q.x + z.y * q.y + z.z * q.z + z.w * q.w;
        }
        e_s[jj][h] = (jj < dg) ? __expf(acc * INV_SQRT_SUB) : 0.f;
    }
    __syncthreads();

    // phase C: weighted aggregation, 8 scattered loads in flight
    int hh = t >> 5;
    float accV = 0.f, accS = 0.f;
    const float* zbase = ZT + t;
    for (int jj = 0; jj < dg; jj += 8) {
        int j0 = nbr_s[jj],     j1 = nbr_s[jj + 1];
        int j2 = nbr_s[jj + 2], j3 = nbr_s[jj + 3];
        int j4 = nbr_s[jj + 4], j5 = nbr_s[jj + 5];
        int j6 = nbr_s[jj + 6], j7 = nbr_s[jj + 7];
        float v0 = zbase[(size_t)j0 * 128], v1 = zbase[(size_t)j1 * 128];
        float v2 = zbase[(size_t)j2 * 128], v3 = zbase[(size_t)j3 * 128];
        float v4 = zbase[(size_t)j4 * 128], v5 = zbase[(size_t)j5 * 128];
        float v6 = zbase[(size_t)j6 * 128], v7 = zbase[(size_t)j7 * 128];
        float e0 = e_s[jj][hh],     e1 = e_s[jj + 1][hh];
        float e2 = e_s[jj + 2][hh], e3 = e_s[jj + 3][hh];
        float e4 = e_s[jj + 4][hh], e5 = e_s[jj + 5][hh];
        float e6 = e_s[jj + 6][hh], e7 = e_s[jj + 7][hh];
        accV += e0 * v0 + e1 * v1 + e2 * v2 + e3 * v3
              + e4 * v4 + e5 * v5 + e6 * v6 + e7 * v7;
        accS += (e0 + e1) + (e2 + e3) + (e4 + e5) + (e6 + e7);
    }
    agg_s[t] = accV * (ETA / accS);
    __syncthreads();

    // fused epilogue: out[i][t] = soft_thresh(P[i][t] + sum_hs agg[hs]*W2[hs][t])
    float val = pval;
    #pragma unroll 4
    for (int q4 = 0; q4 < 32; ++q4) {
        int hs = q4 * 4;
        float w0 = W2[(hs + 0) * 128 + t];     // coalesced, L2-resident
        float w1 = W2[(hs + 1) * 128 + t];
        float w2v = W2[(hs + 2) * 128 + t];
        float w3 = W2[(hs + 3) * 128 + t];
        float4 a = *(const float4*)&agg_s[hs]; // LDS broadcast
        val += a.x * w0 + a.y * w1 + a.z * w2v + a.w * w3;
    }
    float av = fabsf(val) - th;
    out[(size_t)i * 128 + t] = (av > 0.f) ? copysignf(av, val) : 0.f;
}

extern "C" void kernel_launch(void* const* d_in, const int* in_sizes, int n_in,
                              void* d_out, int out_size, void* d_ws, size_t ws_size,
                              hipStream_t stream) {
    const float* H   = (const float*)d_in[0];
    const float* adj = (const float*)d_in[1];
    const float* U   = (const float*)d_in[2];
    const float* thr = (const float*)d_in[3];
    const float* PW  = (const float*)d_in[4];
    float* out = (float*)d_out;

    char* ws = (char*)d_ws;
    float* ZT    = (float*)(ws);                       // 2 MB
    float* P     = (float*)(ws + (size_t)2097152);     // 2 MB
    float* W2    = (float*)(ws + (size_t)4194304);     // 64 KB
    float* lossp = (float*)(ws + (size_t)4521984);     // 40 B
    int*   nbr   = (int*)  (ws + (size_t)4530176);     // 2 MB
    int*   deg   = (int*)  (ws + (size_t)6627328);     // 16 KB

    front<<<650 + NN / 2, 256, 0, stream>>>(H, U, PW, adj, ZT, P, W2, lossp, nbr, deg);
    attn_core<<<NN, 128, 0, stream>>>(ZT, P, W2, nbr, deg, thr, lossp, out);
}

// Round 11
// 146.198 us; speedup vs baseline: 1.0556x; 1.0137x over previous
//
#include <hip/hip_runtime.h>
#include <hip/hip_bf16.h>
#include <math.h>

#define NN 4096
#define IN_DIM 256
#define OUT_DIM 128
#define HEADS 4
#define SUB 32
#define MAXDEG 128
#define ETA 0.5f
#define INV_SQRT_SUB 0.17677669529663687f

typedef __attribute__((ext_vector_type(8))) short bf16x8;
typedef __attribute__((ext_vector_type(4))) float f32x4;

static __device__ inline short f2bf(float f) {
    unsigned u = __float_as_uint(f);
    unsigned r = u + 0x7FFFu + ((u >> 16) & 1u);
    return (short)(r >> 16);
}
static __device__ inline float bf2f(short s) {
    return __uint_as_float(((unsigned)(unsigned short)s) << 16);
}
#define MFMA16(a, b, c) __builtin_amdgcn_mfma_f32_16x16x32_bf16(a, b, c, 0, 0, 0)

// ---- K1: [ztp 512 | W2 128 | loss 10 | scan 2048] all-independent front ----
#define BLD 264   // B LDS row stride in shorts (16B-aligned rows)
__global__ __launch_bounds__(256) void front(const float* __restrict__ H,
                                             const float* __restrict__ U,
                                             const float* __restrict__ PW,
                                             const float* __restrict__ adj,
                                             float* __restrict__ ZT,
                                             float* __restrict__ P,
                                             float* __restrict__ W2,
                                             float* __restrict__ loss_parts,
                                             int* __restrict__ nbr,
                                             int* __restrict__ deg) {
    int b = blockIdx.x, t = threadIdx.x;
    __shared__ short Bh[32 * BLD];
    __shared__ short Bl[32 * BLD];
    __shared__ float sh[260];
    __shared__ int cnt2[2];

    if (b < 512) {
        // ---- ztp: block = 64 rows x 32 cols, self-contained B conversion ----
        int mtile = b >> 3, cblk = b & 7;
        int m0 = mtile * 64;

        if (cblk < 4) {
            int s = t & 31, dgrp = t >> 5;
            const float* ub = U + cblk * IN_DIM * SUB;
            #pragma unroll 4
            for (int k = 0; k < 32; ++k) {
                int d = dgrp * 32 + k;
                float v = ub[d * SUB + s];
                short hi = f2bf(v);
                Bh[s * BLD + d] = hi;
                Bl[s * BLD + d] = f2bf(v - bf2f(hi));
            }
        } else {
            int oo = t >> 3, o0 = (cblk - 4) * 32;
            const float* pr = PW + (size_t)(o0 + oo) * IN_DIM + (t & 7) * 32;
            #pragma unroll 4
            for (int k = 0; k < 32; ++k) {
                int d = (t & 7) * 32 + k;
                float v = pr[k];
                short hi = f2bf(v);
                Bh[oo * BLD + d] = hi;
                Bl[oo * BLD + d] = f2bf(v - bf2f(hi));
            }
        }
        __syncthreads();

        int w = t >> 6, lane = t & 63;
        int arow = lane & 15, agrp = lane >> 4;
        const float* hrow = H + (size_t)(m0 + w * 16 + arow) * IN_DIM;
        const short* bh0 = &Bh[arow * BLD];
        const short* bl0 = &Bl[arow * BLD];
        const short* bh1 = &Bh[(16 + arow) * BLD];
        const short* bl1 = &Bl[(16 + arow) * BLD];

        f32x4 acc0 = {0.f, 0.f, 0.f, 0.f};
        f32x4 acc1 = {0.f, 0.f, 0.f, 0.f};

        #pragma unroll
        for (int kk = 0; kk < 8; ++kk) {
            int d0 = agrp * 8 + kk * 32;
            float4 f0 = *(const float4*)(hrow + d0);
            float4 f1 = *(const float4*)(hrow + d0 + 4);
            float fv[8] = {f0.x, f0.y, f0.z, f0.w, f1.x, f1.y, f1.z, f1.w};
            bf16x8 a_h, a_l;
            #pragma unroll
            for (int j = 0; j < 8; ++j) {
                short hi = f2bf(fv[j]);
                a_h[j] = hi;
                a_l[j] = f2bf(fv[j] - bf2f(hi));
            }
            bf16x8 b0h = *(const bf16x8*)(bh0 + d0);
            bf16x8 b0l = *(const bf16x8*)(bl0 + d0);
            bf16x8 b1h = *(const bf16x8*)(bh1 + d0);
            bf16x8 b1l = *(const bf16x8*)(bl1 + d0);
            acc0 = MFMA16(a_h, b0h, acc0);
            acc0 = MFMA16(a_h, b0l, acc0);
            acc0 = MFMA16(a_l, b0h, acc0);
            acc1 = MFMA16(a_h, b1h, acc1);
            acc1 = MFMA16(a_h, b1l, acc1);
            acc1 = MFMA16(a_l, b1h, acc1);
        }

        int c0 = cblk * 32;
        float* dst = (c0 < 128) ? ZT : P;
        int colbase = (c0 < 128) ? c0 : c0 - 128;
        #pragma unroll
        for (int i = 0; i < 4; ++i) {
            int row = m0 + w * 16 + agrp * 4 + i;
            dst[(size_t)row * 128 + colbase + arow]      = acc0[i];
            dst[(size_t)row * 128 + colbase + 16 + arow] = acc1[i];
        }
    } else if (b < 640) {
        int hs = b - 512;
        int h = hs >> 5, s = hs & 31;
        sh[t] = U[h * IN_DIM * SUB + t * SUB + s];
        __syncthreads();
        if (t < 128) {
            const float4* pw4 = (const float4*)(PW + t * IN_DIM);
            const float4* u4  = (const float4*)sh;
            float acc = 0.f;
            #pragma unroll 4
            for (int d4 = 0; d4 < 64; ++d4) {
                float4 a = u4[d4], p = pw4[d4];
                acc += a.x * p.x + a.y * p.y + a.z * p.z + a.w * p.w;
            }
            W2[hs * OUT_DIM + t] = acc;       // [hs][o]
        }
    } else if (b < 650) {
        const int pk[10] = {0,0,0,0,1,1,1,2,2,3};
        const int pl[10] = {0,1,2,3,1,2,3,2,3,3};
        int p = b - 640;
        int k = pk[p], l = pl[p];
        int t2 = t & 31;
        int sg = t >> 5;
        const float* Uk = U + k * IN_DIM * SUB;
        const float* Ul = U + l * IN_DIM * SUB;
        float a0 = 0.f, a1 = 0.f, a2 = 0.f, a3 = 0.f;
        #pragma unroll 4
        for (int d = 0; d < IN_DIM; ++d) {
            float ul = Ul[d * SUB + t2];
            float u0 = Uk[d * SUB + sg * 4 + 0];
            float u1 = Uk[d * SUB + sg * 4 + 1];
            float u2 = Uk[d * SUB + sg * 4 + 2];
            float u3 = Uk[d * SUB + sg * 4 + 3];
            a0 += u0 * ul; a1 += u1 * ul; a2 += u2 * ul; a3 += u3 * ul;
        }
        if (k == l) {
            if (sg * 4 + 0 == t2) a0 -= 1.f;
            if (sg * 4 + 1 == t2) a1 -= 1.f;
            if (sg * 4 + 2 == t2) a2 -= 1.f;
            if (sg * 4 + 3 == t2) a3 -= 1.f;
        }
        float local = a0 * a0 + a1 * a1 + a2 * a2 + a3 * a3;
        local += __shfl_xor(local, 32, 64);
        local += __shfl_xor(local, 16, 64);
        local += __shfl_xor(local, 8, 64);
        local += __shfl_xor(local, 4, 64);
        local += __shfl_xor(local, 2, 64);
        local += __shfl_xor(local, 1, 64);
        if ((t & 63) == 0) sh[256 + (t >> 6)] = local;
        __syncthreads();
        if (t == 0) loss_parts[p] = sh[256] + sh[257] + sh[258] + sh[259];
    } else {
        int sb = b - 650;
        int half = t >> 7, u = t & 127;
        int row = sb * 2 + half;
        const float4* row4 = (const float4*)(adj + (size_t)row * NN);
        float4 v[8];
        #pragma unroll
        for (int k = 0; k < 8; ++k) v[k] = row4[u + k * 128];
        if (u == 0) cnt2[half] = 0;
        __syncthreads();
        int* nrow = nbr + row * MAXDEG;
        #pragma unroll
        for (int k = 0; k < 8; ++k) {
            int j0 = (u + k * 128) * 4;
            if (v[k].x > 0.5f) { int p = atomicAdd(&cnt2[half], 1); if (p < MAXDEG) nrow[p] = j0; }
            if (v[k].y > 0.5f) { int p = atomicAdd(&cnt2[half], 1); if (p < MAXDEG) nrow[p] = j0 + 1; }
            if (v[k].z > 0.5f) { int p = atomicAdd(&cnt2[half], 1); if (p < MAXDEG) nrow[p] = j0 + 2; }
            if (v[k].w > 0.5f) { int p = atomicAdd(&cnt2[half], 1); if (p < MAXDEG) nrow[p] = j0 + 3; }
        }
        __syncthreads();
        int dgr = cnt2[half] < MAXDEG ? cnt2[half] : MAXDEG;
        if (u >= dgr) nrow[u] = 0;
        if (u == 0) deg[row] = dgr;
    }
}

// ---- K2: single-loop attention (shuffle softmax) + fused epilogue ----
__global__ __launch_bounds__(128) void attn_core(const float* __restrict__ ZT,
                                                 const float* __restrict__ Pm,
                                                 const float* __restrict__ W2,
                                                 const int* __restrict__ nbr,
                                                 const int* __restrict__ deg,
                                                 const float* __restrict__ threshold,
                                                 const float* __restrict__ loss_parts,
                                                 float* __restrict__ out) {
    int i = blockIdx.x;
    int t = threadIdx.x;
    __shared__ int   nbr_s[MAXDEG];
    __shared__ float z_s[128];
    __shared__ float agg_s[128];

    if (i == 0 && t == 0) {
        float L = 0.f;
        #pragma unroll
        for (int p = 0; p < 10; ++p) L += loss_parts[p];
        out[(size_t)NN * OUT_DIM] = L;
    }

    // front loads issued immediately
    int dg = deg[i];
    int nb = nbr[i * MAXDEG + t];
    float zq = ZT[(size_t)i * 128 + t];
    float pval = Pm[(size_t)i * 128 + t];
    float th = threshold[t];

    nbr_s[t] = nb;
    z_s[t] = zq;
    __syncthreads();

    int hh = t >> 5;          // head
    int sl = t & 31;          // slot within head group
    const float4* qr = (const float4*)(&z_s[hh * 32]);   // my head's q (LDS broadcast)
    const float* zcol = ZT + t;                           // aggregation column

    float accV = 0.f, accS = 0.f;
    int ntiles = (dg + 31) >> 5;
    for (int tile = 0; tile < ntiles; ++tile) {
        int jj = tile * 32 + sl;
        int j = nbr_s[jj];                      // tail entries are 0 (safe)
        const float4* zr = (const float4*)(ZT + (size_t)j * 128 + hh * 32);
        float d = 0.f;
        #pragma unroll
        for (int k = 0; k < 8; ++k) {
            float4 z = zr[k];
            float4 q = qr[k];
            d += z.x * q.x + z.y * q.y + z.z * q.z + z.w * q.w;
        }
        float e = (jj < dg) ? __expf(d * INV_SQRT_SUB) : 0.f;
        accS += e;

        int base = tile * 32;
        #pragma unroll
        for (int u = 0; u < 32; u += 8) {
            float e0 = __shfl(e, u + 0, 32), e1 = __shfl(e, u + 1, 32);
            float e2 = __shfl(e, u + 2, 32), e3 = __shfl(e, u + 3, 32);
            float e4 = __shfl(e, u + 4, 32), e5 = __shfl(e, u + 5, 32);
            float e6 = __shfl(e, u + 6, 32), e7 = __shfl(e, u + 7, 32);
            int j0 = nbr_s[base + u + 0], j1 = nbr_s[base + u + 1];
            int j2 = nbr_s[base + u + 2], j3 = nbr_s[base + u + 3];
            int j4 = nbr_s[base + u + 4], j5 = nbr_s[base + u + 5];
            int j6 = nbr_s[base + u + 6], j7 = nbr_s[base + u + 7];
            float v0 = zcol[(size_t)j0 * 128], v1 = zcol[(size_t)j1 * 128];
            float v2 = zcol[(size_t)j2 * 128], v3 = zcol[(size_t)j3 * 128];
            float v4 = zcol[(size_t)j4 * 128], v5 = zcol[(size_t)j5 * 128];
            float v6 = zcol[(size_t)j6 * 128], v7 = zcol[(size_t)j7 * 128];
            accV += e0 * v0 + e1 * v1 + e2 * v2 + e3 * v3
                  + e4 * v4 + e5 * v5 + e6 * v6 + e7 * v7;
        }
    }
    // softmax denominator: butterfly over the 32-lane head group
    accS += __shfl_xor(accS, 16, 32);
    accS += __shfl_xor(accS, 8, 32);
    accS += __shfl_xor(accS, 4, 32);
    accS += __shfl_xor(accS, 2, 32);
    accS += __shfl_xor(accS, 1, 32);

    agg_s[t] = accV * (ETA / accS);
    __syncthreads();

    // fused epilogue: out[i][t] = soft_thresh(P[i][t] + sum_hs agg[hs]*W2[hs][t])
    float val = pval;
    #pragma unroll 4
    for (int q4 = 0; q4 < 32; ++q4) {
        int hs = q4 * 4;
        float w0 = W2[(hs + 0) * 128 + t];
        float w1 = W2[(hs + 1) * 128 + t];
        float w2v = W2[(hs + 2) * 128 + t];
        float w3 = W2[(hs + 3) * 128 + t];
        float4 a = *(const float4*)&agg_s[hs];
        val += a.x * w0 + a.y * w1 + a.z * w2v + a.w * w3;
    }
    float av = fabsf(val) - th;
    out[(size_t)i * 128 + t] = (av > 0.f) ? copysignf(av, val) : 0.f;
}

extern "C" void kernel_launch(void* const* d_in, const int* in_sizes, int n_in,
                              void* d_out, int out_size, void* d_ws, size_t ws_size,
                              hipStream_t stream) {
    const float* H   = (const float*)d_in[0];
    const float* adj = (const float*)d_in[1];
    const float* U   = (const float*)d_in[2];
    const float* thr = (const float*)d_in[3];
    const float* PW  = (const float*)d_in[4];
    float* out = (float*)d_out;

    char* ws = (char*)d_ws;
    float* ZT    = (float*)(ws);                       // 2 MB
    float* P     = (float*)(ws + (size_t)2097152);     // 2 MB
    float* W2    = (float*)(ws + (size_t)4194304);     // 64 KB
    float* lossp = (float*)(ws + (size_t)4521984);     // 40 B
    int*   nbr   = (int*)  (ws + (size_t)4530176);     // 2 MB
    int*   deg   = (int*)  (ws + (size_t)6627328);     // 16 KB

    front<<<650 + NN / 2, 256, 0, stream>>>(H, U, PW, adj, ZT, P, W2, lossp, nbr, deg);
    attn_core<<<NN, 128, 0, stream>>>(ZT, P, W2, nbr, deg, thr, lossp, out);
}